// Round 1
// baseline (486.573 us; speedup 1.0000x reference)
//
#include <hip/hip_runtime.h>
#include <math.h>

// Variance-gamma MC option pricer.
// incr = THETA*gamma + SIGMA*sqrt(gamma)*z ; X = cumsum(incr) sampled at `indices`-1
// Sm = S0*exp((r+w)*im*h + Xm) ; four payoff tables, mean over paths, discounted.

#define NSTEPS 365
#define NM     12
#define NK     21
#define CH     30      // steps staged per chunk
#define STRIDE 31      // CH padded to odd -> conflict-free per-thread LDS reads
#define P      128     // paths per block (2 waves)

#define THETA_F (-0.1436f)
#define SIGMA_F (0.1213f)
#define THETA_D (-0.1436)
#define MU_D    (0.1686)
#define SIGMA_D (0.1213)

__global__ __launch_bounds__(P) void vg_paths_kernel(
    const float* __restrict__ S0p, const float* __restrict__ ratep,
    const int* __restrict__ indices, const float* __restrict__ z,
    const float* __restrict__ gam, const float* __restrict__ Kc,
    const float* __restrict__ Kp, float* __restrict__ acc, int MC)
{
    __shared__ float zs[P * STRIDE];
    __shared__ float gs[P * STRIDE];

    const int tid = threadIdx.x;
    const int p0  = blockIdx.x * P;
    const int pvalid = min(P, MC - p0);

    const int h4 = tid >> 5;   // half-wave id 0..3
    const int ln = tid & 31;   // lane within half-wave

    float X = 0.0f;
    float xm[NM];

    int b0 = 0;
    for (int m = 0; m < NM; ++m) {
        const int b1 = indices[m];           // uniform across block
        for (int c0 = b0; c0 < b1; c0 += CH) {
            const int L = min(CH, b1 - c0);
            // ---- coalesced staging: each half-wave loads one 120B row-chunk ----
            for (int r = h4; r < P; r += 4) {
                const int p = p0 + r;
                if (ln < L && p < MC) {
                    const int g = p * NSTEPS + c0 + ln;
                    zs[r * STRIDE + ln] = z[g];
                    gs[r * STRIDE + ln] = gam[g];
                }
            }
            __syncthreads();
            // ---- per-thread segment partial sum from LDS ----
            if (tid < pvalid) {
                const float* zr = &zs[tid * STRIDE];
                const float* gr = &gs[tid * STRIDE];
                float s = 0.0f;
                #pragma unroll 6
                for (int c = 0; c < L; ++c) {
                    const float g = gr[c];
                    s += THETA_F * g + SIGMA_F * sqrtf(g) * zr[c];
                }
                X += s;
            }
            __syncthreads();
        }
        xm[m] = X;
        b0 = b1;
    }

    // ---- Sm per path into LDS (reuse zs buffer) ----
    float* Sms = zs;                 // P*13 floats <= P*STRIDE
    const float r_  = ratep[0];
    const float s0_ = S0p[0];
    const float w   = (float)((1.0 / MU_D) *
                      log(1.0 - THETA_D * MU_D - SIGMA_D * SIGMA_D * MU_D / 2.0));
    const float hh  = 1.0f / (float)NSTEPS;
    if (tid < pvalid) {
        #pragma unroll
        for (int m = 0; m < NM; ++m) {
            const float im = (float)indices[m];
            Sms[tid * 13 + m] = s0_ * __expf((r_ + w) * im * hh + xm[m]) ;
        }
    }
    __syncthreads();

    // ---- block-level payoff partial sums, one atomic per (cell,type) ----
    for (int cell = tid; cell < NM * NK; cell += P) {
        const int m = cell / NK;
        const int k = cell - m * NK;
        const float kc = Kc[k], kp = Kp[k];
        float s_c = 0.f, s_p = 0.f, s_ckp = 0.f, s_pkc = 0.f;
        for (int p = 0; p < pvalid; ++p) {
            const float S = Sms[p * 13 + m];
            s_c   += fmaxf(S - kc, 0.f);
            s_p   += fmaxf(kp - S, 0.f);
            s_ckp += fmaxf(S - kp, 0.f);
            s_pkc += fmaxf(kc - S, 0.f);
        }
        atomicAdd(&acc[0 * NM * NK + cell], s_c);
        atomicAdd(&acc[1 * NM * NK + cell], s_p);
        atomicAdd(&acc[2 * NM * NK + cell], s_ckp);
        atomicAdd(&acc[3 * NM * NK + cell], s_pkc);
    }
}

__global__ void vg_finalize_kernel(const float* __restrict__ acc,
                                   const float* __restrict__ ratep,
                                   const int* __restrict__ indices,
                                   float* __restrict__ out, int MC)
{
    const int i = blockIdx.x * blockDim.x + threadIdx.x;
    if (i >= 4 * NM * NK) return;
    const int cell = i % (NM * NK);
    const int m = cell / NK;
    const float r_ = ratep[0];
    const float im = (float)indices[m];
    const float disc = expf(-r_ * im / (float)NSTEPS);
    out[i] = acc[i] * disc / (float)MC;
}

extern "C" void kernel_launch(void* const* d_in, const int* in_sizes, int n_in,
                              void* d_out, int out_size, void* d_ws, size_t ws_size,
                              hipStream_t stream) {
    const float* S0      = (const float*)d_in[0];
    const float* rate    = (const float*)d_in[1];
    const int*   indices = (const int*)d_in[2];
    const float* z       = (const float*)d_in[3];
    const float* gamma_  = (const float*)d_in[4];
    const float* Kc      = (const float*)d_in[5];
    const float* Kp      = (const float*)d_in[6];

    const int MC = in_sizes[3] / NSTEPS;
    float* acc = (float*)d_ws;

    hipMemsetAsync(d_ws, 0, 4 * NM * NK * sizeof(float), stream);

    const int nb = (MC + P - 1) / P;
    vg_paths_kernel<<<nb, P, 0, stream>>>(S0, rate, indices, z, gamma_, Kc, Kp, acc, MC);

    vg_finalize_kernel<<<(4 * NM * NK + 255) / 256, 256, 0, stream>>>(
        acc, rate, indices, (float*)d_out, MC);
}

// Round 2
// 210.121 us; speedup vs baseline: 2.3157x; 2.3157x over previous
//
#include <hip/hip_runtime.h>
#include <math.h>

// Variance-gamma MC option pricer.
// incr = THETA*gamma + SIGMA*sqrt(gamma)*z ; X = cumsum(incr) sampled at indices-1
// Sm = S0*exp((r+w)*im*h + Xm) ; four payoff tables, mean over paths, discounted.
//
// R1: stage via __builtin_amdgcn_global_load_lds (async, width=16) instead of
// VGPR round-trip (R0 was latency-bound at ~1.1 TB/s). LDS rows padded to 32
// floats; XOR swizzle (chunk ^ (row&7)) applied on the GLOBAL source address
// (global_load_lds writes linearly) and again on the LDS read side (rule #21).

#define NSTEPS 365
#define NM     12
#define NK     21
#define ROWS   128    // paths per block (2 waves)
#define RW     32     // padded row width in floats (30 used per segment)

#define THETA_F (-0.1436f)
#define SIGMA_F (0.1213f)
#define THETA_D (-0.1436)
#define MU_D    (0.1686)
#define SIGMA_D (0.1213)

typedef const __attribute__((address_space(1))) void gbl_void;
typedef __attribute__((address_space(3))) void lds_void;

__device__ __forceinline__ void load_lds16(const float* g, const float* l) {
    __builtin_amdgcn_global_load_lds((gbl_void*)g, (lds_void*)l, 16, 0, 0);
}

__global__ __launch_bounds__(ROWS) void vg_paths_kernel(
    const float* __restrict__ S0p, const float* __restrict__ ratep,
    const int* __restrict__ indices, const float* __restrict__ z,
    const float* __restrict__ gam, const float* __restrict__ Kc,
    const float* __restrict__ Kp, float* __restrict__ acc, int MC)
{
    __shared__ float zs[ROWS * RW];
    __shared__ float gs[ROWS * RW];

    const int tid  = threadIdx.x;
    const int wave = tid >> 6;
    const int lane = tid & 63;
    const int p0   = blockIdx.x * ROWS;
    const int pvalid = min(ROWS, MC - p0);
    const int sw   = tid & 7;
    const size_t gmax = (size_t)MC * NSTEPS - 4;   // clamp so 16B loads stay in-bounds

    float X = 0.0f;
    float xm[NM];

    int b0 = 0;
    for (int m = 0; m < NM; ++m) {
        const int b1 = indices[m];                  // uniform across block
        for (int c0 = b0; c0 < b1; c0 += 30) {
            const int L = min(30, b1 - c0);
            // ---- async staging: 16 instrs/array, 1KB LDS each, swizzled global src ----
            for (int inst = wave; inst < 16; inst += 2) {
                const int F    = inst * 256 + lane * 4;       // linear float off in buffer
                const int row  = F >> 5;                      // 0..127
                const int jlog = ((F >> 2) & 7) ^ (row & 7);  // logical 4-float chunk
                const int grow = min(p0 + row, MC - 1);
                size_t g = (size_t)grow * NSTEPS + c0 + 4 * jlog;
                if (g > gmax) g = gmax;
                load_lds16(z + g,   zs + inst * 256);
                load_lds16(gam + g, gs + inst * 256);
            }
            __syncthreads();   // drains vmcnt -> all staged
            // ---- per-thread segment partial sum (swizzled float4 LDS reads) ----
            if (tid < pvalid) {
                const float* zr = &zs[tid * RW];
                const float* gr = &gs[tid * RW];
                float s = 0.0f;
                if (L == 30) {
                    #pragma unroll
                    for (int j = 0; j < 8; ++j) {
                        const int pj = (j ^ sw) << 2;
                        const float4 gq = *(const float4*)&gr[pj];
                        const float4 zq = *(const float4*)&zr[pj];
                        s += THETA_F * gq.x + SIGMA_F * sqrtf(gq.x) * zq.x;
                        s += THETA_F * gq.y + SIGMA_F * sqrtf(gq.y) * zq.y;
                        if (j < 7) {
                            s += THETA_F * gq.z + SIGMA_F * sqrtf(gq.z) * zq.z;
                            s += THETA_F * gq.w + SIGMA_F * sqrtf(gq.w) * zq.w;
                        }
                    }
                } else {
                    for (int c = 0; c < L; ++c) {
                        const int pc = (((c >> 2) ^ sw) << 2) | (c & 3);
                        const float g = gr[pc];
                        s += THETA_F * g + SIGMA_F * sqrtf(g) * zr[pc];
                    }
                }
                X += s;
            }
            __syncthreads();   // all reads done before next chunk overwrites
        }
        xm[m] = X;
        b0 = b1;
    }

    // ---- Sm per path into LDS (reuse zs) ----
    float* Sms = zs;                 // ROWS*13 floats <= ROWS*RW
    const float r_  = ratep[0];
    const float s0_ = S0p[0];
    const float w   = (float)((1.0 / MU_D) *
                      log(1.0 - THETA_D * MU_D - SIGMA_D * SIGMA_D * MU_D / 2.0));
    const float hh  = 1.0f / (float)NSTEPS;
    if (tid < pvalid) {
        #pragma unroll
        for (int m = 0; m < NM; ++m) {
            const float im = (float)indices[m];
            Sms[tid * 13 + m] = s0_ * __expf((r_ + w) * im * hh + xm[m]);
        }
    }
    __syncthreads();

    // ---- block-level payoff partial sums, one atomic per (cell,type) ----
    for (int cell = tid; cell < NM * NK; cell += ROWS) {
        const int m = cell / NK;
        const int k = cell - m * NK;
        const float kc = Kc[k], kp = Kp[k];
        float s_c = 0.f, s_p = 0.f, s_ckp = 0.f, s_pkc = 0.f;
        for (int p = 0; p < pvalid; ++p) {
            const float S = Sms[p * 13 + m];
            s_c   += fmaxf(S - kc, 0.f);
            s_p   += fmaxf(kp - S, 0.f);
            s_ckp += fmaxf(S - kp, 0.f);
            s_pkc += fmaxf(kc - S, 0.f);
        }
        atomicAdd(&acc[0 * NM * NK + cell], s_c);
        atomicAdd(&acc[1 * NM * NK + cell], s_p);
        atomicAdd(&acc[2 * NM * NK + cell], s_ckp);
        atomicAdd(&acc[3 * NM * NK + cell], s_pkc);
    }
}

__global__ void vg_finalize_kernel(const float* __restrict__ acc,
                                   const float* __restrict__ ratep,
                                   const int* __restrict__ indices,
                                   float* __restrict__ out, int MC)
{
    const int i = blockIdx.x * blockDim.x + threadIdx.x;
    if (i >= 4 * NM * NK) return;
    const int cell = i % (NM * NK);
    const int m = cell / NK;
    const float r_ = ratep[0];
    const float im = (float)indices[m];
    const float disc = expf(-r_ * im / (float)NSTEPS);
    out[i] = acc[i] * disc / (float)MC;
}

extern "C" void kernel_launch(void* const* d_in, const int* in_sizes, int n_in,
                              void* d_out, int out_size, void* d_ws, size_t ws_size,
                              hipStream_t stream) {
    const float* S0      = (const float*)d_in[0];
    const float* rate    = (const float*)d_in[1];
    const int*   indices = (const int*)d_in[2];
    const float* z       = (const float*)d_in[3];
    const float* gamma_  = (const float*)d_in[4];
    const float* Kc      = (const float*)d_in[5];
    const float* Kp      = (const float*)d_in[6];

    const int MC = in_sizes[3] / NSTEPS;
    float* acc = (float*)d_ws;

    hipMemsetAsync(d_ws, 0, 4 * NM * NK * sizeof(float), stream);

    const int nb = (MC + ROWS - 1) / ROWS;
    vg_paths_kernel<<<nb, ROWS, 0, stream>>>(S0, rate, indices, z, gamma_, Kc, Kp, acc, MC);

    vg_finalize_kernel<<<(4 * NM * NK + 255) / 256, 256, 0, stream>>>(
        acc, rate, indices, (float*)d_out, MC);
}

// Round 3
// 191.786 us; speedup vs baseline: 2.5371x; 1.0956x over previous
//
#include <hip/hip_runtime.h>
#include <math.h>

// Variance-gamma MC option pricer — R2: wave-per-path, lanes along steps.
// incr = THETA*gamma + SIGMA*sqrt(gamma)*z ; X = cumsum sampled at 30m-1.
// Per 64-step chunk: coalesced dword loads + 6-step shfl_up inclusive scan +
// scalar carry. Boundary steps (29+30m) sit in 2 fixed lanes/chunk -> readlane
// broadcast -> Sm wave-uniform in regs. Payoffs: lane=(m-group,strike) with
// static-indexed register accumulators over 32 paths/wave; LDS block reduce;
// 1008 global atomics/block. No __syncthreads in the hot loop, no staging.

#define NSTEPS 365
#define NM     12
#define NK     21
#define PPW    32            // paths per wave
#define WAVES  4
#define BLOCK  (WAVES * 64)
#define PPB    (WAVES * PPW) // 128 paths per block

#define THETA_F (-0.1436f)
#define SIGMA_F (0.1213f)
#define THETA_D (-0.1436)
#define MU_D    (0.1686)
#define SIGMA_D (0.1213)

__global__ __launch_bounds__(BLOCK) void vg_paths_kernel(
    const float* __restrict__ S0p, const float* __restrict__ ratep,
    const int* __restrict__ indices, const float* __restrict__ z,
    const float* __restrict__ gam, const float* __restrict__ Kc,
    const float* __restrict__ Kp, float* __restrict__ acc, int MC)
{
    __shared__ float lacc[4 * NM * NK];           // 1008 floats
    const int tid = threadIdx.x;
    for (int i = tid; i < 4 * NM * NK; i += BLOCK) lacc[i] = 0.f;

    const int lane = tid & 63;
    const int wv   = tid >> 6;
    const int k    = lane % NK;        // strike col (lane 63 -> dummy)
    const int mg   = lane / NK;        // maturity group 0..2 (lane 63 -> 3)
    const bool lvalid = (lane < 63);

    const float kc  = Kc[k];
    const float kp  = Kp[k];
    const float r_  = ratep[0];
    const float s0_ = S0p[0];
    const float w   = (float)((1.0 / MU_D) *
                      log(1.0 - THETA_D * MU_D - SIGMA_D * SIGMA_D * MU_D / 2.0));
    const float rwh = (r_ + w) / (float)NSTEPS;

    float ab[NM];                       // (r+w)*im*h, static-indexed
    #pragma unroll
    for (int m = 0; m < NM; ++m) ab[m] = rwh * (float)indices[m];

    float accv[4][4];                   // [j][type], all static indices
    #pragma unroll
    for (int j = 0; j < 4; ++j)
        #pragma unroll
        for (int t = 0; t < 4; ++t) accv[j][t] = 0.f;

    const size_t gmax = (size_t)MC * NSTEPS - 1;

    auto loadp = [&](int p, float* zv, float* gv) {
        const int pc = min(p, MC - 1);
        const size_t base = (size_t)pc * NSTEPS + lane;
        #pragma unroll
        for (int c = 0; c < 6; ++c) {
            size_t idx = base + 64 * c;
            if (c == 5) idx = idx > gmax ? gmax : idx;   // lanes >=45 spill into next row
            zv[c] = z[idx];
            gv[c] = gam[idx];
        }
    };

    auto process = [&](const float* zv, const float* gv, bool pv) {
        float S[NM];
        float carry = 0.f;
        #pragma unroll
        for (int c = 0; c < 6; ++c) {
            const float g = gv[c];
            float v = fmaf(THETA_F, g, SIGMA_F * sqrtf(g) * zv[c]);
            if (c == 5 && lane >= 45) v = 0.f;
            #pragma unroll
            for (int d = 1; d < 64; d <<= 1) {     // inclusive scan
                const float t = __shfl_up(v, d, 64);
                if (lane >= d) v += t;
            }
            const float x0 = carry + __shfl(v, 29 - 4 * c, 64);
            const float x1 = carry + __shfl(v, 59 - 4 * c, 64);
            S[2 * c]     = s0_ * __expf(ab[2 * c] + x0);
            S[2 * c + 1] = s0_ * __expf(ab[2 * c + 1] + x1);
            carry += __shfl(v, 63, 64);
        }
        if (!pv) return;                            // wave-uniform guard
        #pragma unroll
        for (int j = 0; j < 4; ++j) {
            const float Sj = (mg == 0) ? S[j] : (mg == 1) ? S[j + 4] : S[j + 8];
            accv[j][0] += fmaxf(Sj - kc, 0.f);
            accv[j][1] += fmaxf(kp - Sj, 0.f);
            accv[j][2] += fmaxf(Sj - kp, 0.f);
            accv[j][3] += fmaxf(kc - Sj, 0.f);
        }
    };

    // ---- hand-double-buffered path loop: loads for p+1 overlap scan of p ----
    const int p0 = blockIdx.x * PPB + wv * PPW;
    float zA[6], gA[6], zB[6], gB[6];
    loadp(p0, zA, gA);
    #pragma unroll 1
    for (int pp = 0; pp < PPW; pp += 2) {
        loadp(p0 + pp + 1, zB, gB);
        process(zA, gA, p0 + pp < MC);
        loadp(p0 + pp + 2, zA, gA);      // last iter: clamped, discarded
        process(zB, gB, p0 + pp + 1 < MC);
    }

    // ---- block reduce: regs -> LDS -> global atomics ----
    __syncthreads();
    if (lvalid) {
        #pragma unroll
        for (int j = 0; j < 4; ++j) {
            const int cell = (4 * mg + j) * NK + k;
            #pragma unroll
            for (int t = 0; t < 4; ++t)
                atomicAdd(&lacc[t * NM * NK + cell], accv[j][t]);
        }
    }
    __syncthreads();
    for (int i = tid; i < 4 * NM * NK; i += BLOCK)
        atomicAdd(&acc[i], lacc[i]);
}

__global__ void vg_finalize_kernel(const float* __restrict__ acc,
                                   const float* __restrict__ ratep,
                                   const int* __restrict__ indices,
                                   float* __restrict__ out, int MC)
{
    const int i = blockIdx.x * blockDim.x + threadIdx.x;
    if (i >= 4 * NM * NK) return;
    const int cell = i % (NM * NK);
    const int m = cell / NK;
    const float r_ = ratep[0];
    const float im = (float)indices[m];
    const float disc = expf(-r_ * im / (float)NSTEPS);
    out[i] = acc[i] * disc / (float)MC;
}

extern "C" void kernel_launch(void* const* d_in, const int* in_sizes, int n_in,
                              void* d_out, int out_size, void* d_ws, size_t ws_size,
                              hipStream_t stream) {
    const float* S0      = (const float*)d_in[0];
    const float* rate    = (const float*)d_in[1];
    const int*   indices = (const int*)d_in[2];
    const float* z       = (const float*)d_in[3];
    const float* gamma_  = (const float*)d_in[4];
    const float* Kc      = (const float*)d_in[5];
    const float* Kp      = (const float*)d_in[6];

    const int MC = in_sizes[3] / NSTEPS;
    float* acc = (float*)d_ws;

    hipMemsetAsync(d_ws, 0, 4 * NM * NK * sizeof(float), stream);

    const int nb = (MC + PPB - 1) / PPB;
    vg_paths_kernel<<<nb, BLOCK, 0, stream>>>(S0, rate, indices, z, gamma_, Kc, Kp, acc, MC);

    vg_finalize_kernel<<<(4 * NM * NK + 255) / 256, 256, 0, stream>>>(
        acc, rate, indices, (float*)d_out, MC);
}